// Round 2
// baseline (5897.441 us; speedup 1.0000x reference)
//
#include <hip/hip_runtime.h>

// Problem: BiLSTM-CRF tagger NLL (forward only).
// B=64, L=128, E=300, H=256 (per dir), 4H=1024, T=64, V=50000.
// Output: single f32 scalar = mean(log_z - numerator).
//
// ws layout (float units):
//   XP_OFF   = 0           : xp[2][8192][1024]   (input projections, biases folded)
//   LSTM_OFF = 16777216    : lstm_out[8192][512] (cols 0-255 fwd h, 256-511 bwd h)
//   EM_OFF   = 20971520    : emissions[8192][64]
//   WBF_OFF  = 21495808    : w_hh fp8 repacked, 2*64*1024 dwords (512 KB)
//   NLL_OFF  = 21757952    : per-batch nll [64]

#define XP_OFF   0
#define LSTM_OFF 16777216
#define EM_OFF   20971520
#define WBF_OFF  21495808
#define NLL_OFF  21757952

typedef float v2f __attribute__((ext_vector_type(2)));

__device__ __forceinline__ float sigmf(float x) { return 1.f / (1.f + __expf(-x)); }
__device__ __forceinline__ float tanhfast(float x) {
    float t = __expf(2.f * x);
    return 1.f - 2.f / (t + 1.f);
}

// ---- fp8 e4m3fn encode (RNE), |x| <= 4.0 guaranteed by caller ----
__device__ __forceinline__ unsigned enc8(float x) {
    unsigned s = (__float_as_uint(x) >> 31) << 7;
    float a = fabsf(x);
    if (a >= 0.015625f) {                    // normal: 2^-6 .. 4.0
        int e; float m = frexpf(a, &e);      // a = m*2^e, m in [0.5,1)
        float q = rintf(m * 16.f);           // in [8,16]
        if (q >= 16.f) { q = 8.f; e += 1; }
        int E = e - 1 + 7;
        return s | (unsigned)(E << 3) | (unsigned)((int)q - 8);
    } else {                                 // denormal: multiples of 2^-9
        float q = rintf(a * 512.f);          // 0..8
        if (q >= 8.f) return s | (1u << 3);  // rounds up to 2^-6
        return s | (unsigned)(int)q;
    }
}

// ---- fp8 e4m3fn pair decode ----
__device__ __forceinline__ v2f dec2lo(unsigned v) {
#if __has_builtin(__builtin_amdgcn_cvt_pk_f32_fp8)
    return __builtin_amdgcn_cvt_pk_f32_fp8((int)v, false);
#else
    unsigned b0 = v & 0xffu, b1 = (v >> 8) & 0xffu;
    v2f r;
    r.x = __uint_as_float(((b0 & 0x80u) << 24) | ((b0 & 0x7fu) << 20)) * 1.3292279957849159e36f;
    r.y = __uint_as_float(((b1 & 0x80u) << 24) | ((b1 & 0x7fu) << 20)) * 1.3292279957849159e36f;
    return r;
#endif
}
__device__ __forceinline__ v2f dec2hi(unsigned v) {
#if __has_builtin(__builtin_amdgcn_cvt_pk_f32_fp8)
    return __builtin_amdgcn_cvt_pk_f32_fp8((int)v, true);
#else
    unsigned b0 = (v >> 16) & 0xffu, b1 = (v >> 24) & 0xffu;
    v2f r;
    r.x = __uint_as_float(((b0 & 0x80u) << 24) | ((b0 & 0x7fu) << 20)) * 1.3292279957849159e36f;
    r.y = __uint_as_float(((b1 & 0x80u) << 24) | ((b1 & 0x7fu) << 20)) * 1.3292279957849159e36f;
    return r;
#endif
}

// ---------------- K0: repack w_hh (f32 -> fp8 e4m3, scaled x64) ----------------
// out[((dir*64 + kq)*1024 + r)] : byte b = fp8(64 * w[r][4*kq+b])
__global__ __launch_bounds__(256) void cvt_whh_fp8(
    const float* __restrict__ wf, const float* __restrict__ wb,
    unsigned int* __restrict__ out)
{
    int d = blockIdx.x * 256 + threadIdx.x;   // 0 .. 131071
    int r   = d & 1023;
    int kq  = (d >> 10) & 63;
    int dir = d >> 16;
    const float* w = dir ? wb : wf;
    const float* src = w + (size_t)r * 256 + kq * 4;
    unsigned o = 0;
    #pragma unroll
    for (int i = 0; i < 4; ++i) o |= enc8(src[i] * 64.f) << (8 * i);
    out[d] = o;
}

// ---------------- K1: fused gather + input projection GEMM ----------------
// xp[dir][m][n] = emb[sent[m]] . w_ih_dir[n] + b_ih[n] + b_hh[n]
// M=8192, N=2048 (2 dirs x 1024), K=300.  BM=BN=128, BK=60.
__global__ __launch_bounds__(256) void xp_gemm(
    const int* __restrict__ sent, const float* __restrict__ emb,
    const float* __restrict__ w_ih_f, const float* __restrict__ b_ih_f, const float* __restrict__ b_hh_f,
    const float* __restrict__ w_ih_b, const float* __restrict__ b_ih_b, const float* __restrict__ b_hh_b,
    float* __restrict__ xp)
{
    __shared__ float as[60][128];
    __shared__ float bs[60][128];
    __shared__ int sidx[128];
    const int tid = threadIdx.x;
    const int m0 = blockIdx.x * 128;
    const int nt = blockIdx.y;
    const int dir = nt >> 3;
    const int n0 = (nt & 7) * 128;
    const float* w_ih = dir ? w_ih_b : w_ih_f;
    const float* bi = dir ? b_ih_b : b_ih_f;
    const float* bh = dir ? b_hh_b : b_hh_f;
    if (tid < 128) sidx[tid] = sent[m0 + tid];
    __syncthreads();
    const int lr = tid >> 1;
    const int lh = tid & 1;
    const int rb = (tid & 15) * 4;
    const int cb = (tid >> 4) * 4;
    float acc[8][8] = {};
    const float* asrc = emb  + (size_t)sidx[lr] * 300 + lh * 30;
    const float* bsrc = w_ih + (size_t)(n0 + lr) * 300 + lh * 30;
    for (int kc = 0; kc < 5; ++kc) {
        #pragma unroll
        for (int i = 0; i < 15; ++i) {
            float2 va = *(const float2*)(asrc + 2 * i);
            as[lh * 30 + 2 * i][lr]     = va.x;
            as[lh * 30 + 2 * i + 1][lr] = va.y;
            float2 vb = *(const float2*)(bsrc + 2 * i);
            bs[lh * 30 + 2 * i][lr]     = vb.x;
            bs[lh * 30 + 2 * i + 1][lr] = vb.y;
        }
        asrc += 60; bsrc += 60;
        __syncthreads();
        #pragma unroll 4
        for (int kk = 0; kk < 60; ++kk) {
            float a[8], b[8];
            *(float4*)(a)     = *(const float4*)&as[kk][rb];
            *(float4*)(a + 4) = *(const float4*)&as[kk][64 + rb];
            *(float4*)(b)     = *(const float4*)&bs[kk][cb];
            *(float4*)(b + 4) = *(const float4*)&bs[kk][64 + cb];
            #pragma unroll
            for (int i = 0; i < 8; ++i)
                #pragma unroll
                for (int jj = 0; jj < 8; ++jj)
                    acc[i][jj] += a[i] * b[jj];
        }
        __syncthreads();
    }
    float bias[8];
    #pragma unroll
    for (int jj = 0; jj < 4; ++jj) {
        bias[jj]     = bi[n0 + cb + jj]      + bh[n0 + cb + jj];
        bias[4 + jj] = bi[n0 + 64 + cb + jj] + bh[n0 + 64 + cb + jj];
    }
    float* outp = xp + (size_t)dir * 8388608 + (size_t)m0 * 1024 + n0;
    #pragma unroll
    for (int i = 0; i < 8; ++i) {
        int r = (i < 4) ? (rb + i) : (64 + rb + i - 4);
        float4 o0 = make_float4(acc[i][0] + bias[0], acc[i][1] + bias[1],
                                acc[i][2] + bias[2], acc[i][3] + bias[3]);
        float4 o1 = make_float4(acc[i][4] + bias[4], acc[i][5] + bias[5],
                                acc[i][6] + bias[6], acc[i][7] + bias[7]);
        *(float4*)&outp[(size_t)r * 1024 + cb]      = o0;
        *(float4*)&outp[(size_t)r * 1024 + 64 + cb] = o1;
    }
}

// ---------------- K2: LSTM recurrence, fp8 weights register-resident ----------------
// 128 blocks = (dir, batch). 512 threads; thread t owns gate rows t and t+512.
// Weights: 2 x 64 packed-fp8 dwords per thread, held in VGPRs for all 128 steps.
__global__ __launch_bounds__(512, 2) void lstm_rec(
    const float* __restrict__ xp, const unsigned int* __restrict__ w8,
    float* __restrict__ lstm_out)
{
    const int bid = blockIdx.x;
    const int dir = bid >> 6;
    const int b = bid & 63;
    const int t = threadIdx.x;
    __shared__ __align__(16) float hs[256];
    __shared__ float gs[1024];

    unsigned wA[64], wB[64];
    const unsigned* wp = w8 + (size_t)dir * 65536;
    #pragma unroll
    for (int kq = 0; kq < 64; ++kq) {
        wA[kq] = wp[kq * 1024 + t];
        wB[kq] = wp[kq * 1024 + t + 512];
    }
    float c = 0.f;
    if (t < 256) hs[t] = 0.f;
    const float* xpb = xp + (size_t)dir * 8388608 + (size_t)b * 131072;
    const int dl = dir ? -1 : 1;
    int l = dir ? 127 : 0;
    float xr0 = xpb[l * 1024 + t];
    float xr1 = xpb[l * 1024 + t + 512];
    __syncthreads();

    for (int s = 0; s < 128; ++s) {
        float nx0 = 0.f, nx1 = 0.f;
        if (s < 127) {                        // prefetch next step's xp
            const float* xn = xpb + (size_t)(l + dl) * 1024;
            nx0 = xn[t]; nx1 = xn[t + 512];
        }
        float a0 = 0.f, a1 = 0.f, a2 = 0.f, a3 = 0.f;
        #pragma unroll
        for (int kq = 0; kq < 64; ++kq) {
            float4 h4 = *((const float4*)hs + kq);   // uniform-address broadcast
            unsigned wa = wA[kq], wb_ = wB[kq];
            v2f p0 = dec2lo(wa), p1 = dec2hi(wa);
            a0 += p0.x * h4.x + p0.y * h4.y;
            a1 += p1.x * h4.z + p1.y * h4.w;
            v2f q0 = dec2lo(wb_), q1 = dec2hi(wb_);
            a2 += q0.x * h4.x + q0.y * h4.y;
            a3 += q1.x * h4.z + q1.y * h4.w;
        }
        gs[t]       = (a0 + a1) * 0.015625f + xr0;   // /64 undoes encode scale
        gs[t + 512] = (a2 + a3) * 0.015625f + xr1;
        __syncthreads();
        if (t < 256) {
            float gi = gs[t], gf = gs[t + 256], gg = gs[t + 512], go = gs[t + 768];
            c = sigmf(gf) * c + sigmf(gi) * tanhfast(gg);
            float h = sigmf(go) * tanhfast(c);
            hs[t] = h;
            lstm_out[(size_t)(b * 128 + l) * 512 + dir * 256 + t] = h;
        }
        __syncthreads();
        xr0 = nx0; xr1 = nx1; l += dl;
    }
}

// ---------------- K3: emissions GEMM ----------------
__global__ __launch_bounds__(256) void emis_gemm(
    const float* __restrict__ lo, const float* __restrict__ w_out,
    const float* __restrict__ b_out, float* __restrict__ em)
{
    __shared__ float as[64][64];
    __shared__ float bs[64][64];
    const int tid = threadIdx.x;
    const int m0 = blockIdx.x * 64;
    const int mr = tid & 63;
    const int kq = tid >> 6;
    const int rb = (tid & 15) * 4;
    const int cb = (tid >> 4) * 4;
    float acc[4][4] = {};
    for (int kc = 0; kc < 8; ++kc) {
        const int k0 = kc * 64;
        #pragma unroll
        for (int i = 0; i < 4; ++i) {
            const int k = kq * 16 + 4 * i;
            float4 va = *(const float4*)&lo[(size_t)(m0 + mr) * 512 + k0 + k];
            as[k][mr] = va.x; as[k + 1][mr] = va.y; as[k + 2][mr] = va.z; as[k + 3][mr] = va.w;
            float4 vb = *(const float4*)&w_out[(size_t)mr * 512 + k0 + k];
            bs[k][mr] = vb.x; bs[k + 1][mr] = vb.y; bs[k + 2][mr] = vb.z; bs[k + 3][mr] = vb.w;
        }
        __syncthreads();
        #pragma unroll 8
        for (int kk = 0; kk < 64; ++kk) {
            float a[4], bb[4];
            *(float4*)a  = *(const float4*)&as[kk][rb];
            *(float4*)bb = *(const float4*)&bs[kk][cb];
            #pragma unroll
            for (int i = 0; i < 4; ++i)
                #pragma unroll
                for (int jj = 0; jj < 4; ++jj)
                    acc[i][jj] += a[i] * bb[jj];
        }
        __syncthreads();
    }
    float4 bo = *(const float4*)&b_out[cb];
    #pragma unroll
    for (int i = 0; i < 4; ++i) {
        float4 o = make_float4(acc[i][0] + bo.x, acc[i][1] + bo.y,
                               acc[i][2] + bo.z, acc[i][3] + bo.w);
        *(float4*)&em[(size_t)(m0 + rb + i) * 64 + cb] = o;
    }
}

// ---------------- K4: CRF numerator + forward algorithm ----------------
__global__ __launch_bounds__(256) void crf_kernel(
    const float* __restrict__ em, const int* __restrict__ tags,
    const float* __restrict__ start_t, const float* __restrict__ end_t,
    const float* __restrict__ trans, float* __restrict__ nll)
{
    const int b = blockIdx.x;
    const int tid = threadIdx.x;
    const int j = tid & 63;
    const int q = tid >> 6;
    __shared__ float s_lds[64];
    __shared__ float part[4][64];
    __shared__ float m_sh, num_sh;
    float tr[16];
    #pragma unroll
    for (int ii = 0; ii < 16; ++ii) tr[ii] = trans[(q * 16 + ii) * 64 + j];
    const float* emb_b = em + (size_t)b * 8192;
    const int* tg_b = tags + b * 128;
    float numpart = 0.f;
    if (tid < 128) {
        int l = tid;
        int tg = tg_b[l];
        numpart = emb_b[l * 64 + tg];
        if (l < 127) numpart += trans[tg * 64 + tg_b[l + 1]];
        if (l == 0)  numpart += start_t[tg];
        if (l == 127) numpart += end_t[tg];
    }
    float red = numpart;
    #pragma unroll
    for (int off = 32; off >= 1; off >>= 1) red += __shfl_xor(red, off);
    if (j == 0) part[q][0] = red;
    if (q == 0) s_lds[j] = start_t[j] + emb_b[j];
    __syncthreads();
    if (tid == 0) num_sh = part[0][0] + part[1][0] + part[2][0] + part[3][0];
    __syncthreads();
    for (int l = 1; l < 128; ++l) {
        if (q == 0) {
            float v = s_lds[j];
            #pragma unroll
            for (int off = 32; off >= 1; off >>= 1) v = fmaxf(v, __shfl_xor(v, off));
            if (j == 0) m_sh = v;
        }
        __syncthreads();
        const float m = m_sh;
        float sv[16];
        #pragma unroll
        for (int t4 = 0; t4 < 4; ++t4) {
            float4 v = *(const float4*)&s_lds[q * 16 + 4 * t4];
            sv[4 * t4] = v.x; sv[4 * t4 + 1] = v.y; sv[4 * t4 + 2] = v.z; sv[4 * t4 + 3] = v.w;
        }
        float acc = 0.f;
        #pragma unroll
        for (int ii = 0; ii < 16; ++ii) acc += __expf(sv[ii] + tr[ii] - m);
        part[q][j] = acc;
        __syncthreads();
        if (q == 0) {
            float t = part[0][j] + part[1][j] + part[2][j] + part[3][j];
            s_lds[j] = m + __logf(t) + emb_b[l * 64 + j];
        }
    }
    if (q == 0) {
        float v = s_lds[j] + end_t[j];
        float mm = v;
        #pragma unroll
        for (int off = 32; off >= 1; off >>= 1) mm = fmaxf(mm, __shfl_xor(mm, off));
        float e = __expf(v - mm);
        #pragma unroll
        for (int off = 32; off >= 1; off >>= 1) e += __shfl_xor(e, off);
        if (j == 0) nll[b] = (mm + __logf(e)) - num_sh;
    }
}

// ---------------- K5: final mean ----------------
__global__ void finalize(const float* __restrict__ nll, float* __restrict__ out)
{
    int j = threadIdx.x;
    float v = nll[j];
    #pragma unroll
    for (int off = 32; off >= 1; off >>= 1) v += __shfl_xor(v, off);
    if (j == 0) out[0] = v * (1.f / 64.f);
}

extern "C" void kernel_launch(void* const* d_in, const int* in_sizes, int n_in,
                              void* d_out, int out_size, void* d_ws, size_t ws_size,
                              hipStream_t stream) {
    const int* sent      = (const int*)d_in[0];
    const int* tags      = (const int*)d_in[1];
    const float* emb     = (const float*)d_in[2];
    const float* w_ih_f  = (const float*)d_in[3];
    const float* w_hh_f  = (const float*)d_in[4];
    const float* b_ih_f  = (const float*)d_in[5];
    const float* b_hh_f  = (const float*)d_in[6];
    const float* w_ih_b  = (const float*)d_in[7];
    const float* w_hh_b  = (const float*)d_in[8];
    const float* b_ih_b  = (const float*)d_in[9];
    const float* b_hh_b  = (const float*)d_in[10];
    const float* w_out   = (const float*)d_in[11];
    const float* b_out   = (const float*)d_in[12];
    const float* start_t = (const float*)d_in[13];
    const float* end_t   = (const float*)d_in[14];
    const float* trans   = (const float*)d_in[15];

    float* ws = (float*)d_ws;
    float* xp        = ws + XP_OFF;
    float* lstm_out  = ws + LSTM_OFF;
    float* em        = ws + EM_OFF;
    unsigned int* w8 = (unsigned int*)(ws + WBF_OFF);
    float* nll       = ws + NLL_OFF;

    cvt_whh_fp8<<<dim3(512), dim3(256), 0, stream>>>(w_hh_f, w_hh_b, w8);
    xp_gemm<<<dim3(64, 16), dim3(256), 0, stream>>>(sent, emb,
        w_ih_f, b_ih_f, b_hh_f, w_ih_b, b_ih_b, b_hh_b, xp);
    lstm_rec<<<dim3(128), dim3(512), 0, stream>>>(xp, w8, lstm_out);
    emis_gemm<<<dim3(128), dim3(256), 0, stream>>>(lstm_out, w_out, b_out, em);
    crf_kernel<<<dim3(64), dim3(256), 0, stream>>>(em, tags, start_t, end_t, trans, nll);
    finalize<<<dim3(1), dim3(64), 0, stream>>>(nll, (float*)d_out);
}

// Round 3
// 4636.985 us; speedup vs baseline: 1.2718x; 1.2718x over previous
//
#include <hip/hip_runtime.h>

// Problem: BiLSTM-CRF tagger NLL (forward only).
// B=64, L=128, E=300, H=256 (per dir), 4H=1024, T=64, V=50000.
// Output: single f32 scalar = mean(log_z - numerator).
//
// ws layout (float units):
//   XP_OFF   = 0           : xp[2][8192][1024]   (input projections, biases folded)
//   LSTM_OFF = 16777216    : lstm_out[8192][512] (cols 0-255 fwd h, 256-511 bwd h)
//   EM_OFF   = 20971520    : emissions[8192][64]
//   WBF_OFF  = 21495808    : w_hh fp8 repacked, 2*64*1024 dwords (512 KB)
//   NLL_OFF  = 21757952    : per-batch nll [64]

#define XP_OFF   0
#define LSTM_OFF 16777216
#define EM_OFF   20971520
#define WBF_OFF  21495808
#define NLL_OFF  21757952

typedef float v2f __attribute__((ext_vector_type(2)));

__device__ __forceinline__ float sigmf(float x) { return 1.f / (1.f + __expf(-x)); }
__device__ __forceinline__ float tanhfast(float x) {
    float t = __expf(2.f * x);
    return 1.f - 2.f / (t + 1.f);
}

// ---- fp8 e4m3fn encode (RNE), |x| <= 4.0 guaranteed by caller ----
__device__ __forceinline__ unsigned enc8(float x) {
    unsigned s = (__float_as_uint(x) >> 31) << 7;
    float a = fabsf(x);
    if (a >= 0.015625f) {                    // normal: 2^-6 .. 4.0
        int e; float m = frexpf(a, &e);      // a = m*2^e, m in [0.5,1)
        float q = rintf(m * 16.f);           // in [8,16]
        if (q >= 16.f) { q = 8.f; e += 1; }
        int E = e - 1 + 7;
        return s | (unsigned)(E << 3) | (unsigned)((int)q - 8);
    } else {                                 // denormal: multiples of 2^-9
        float q = rintf(a * 512.f);          // 0..8
        if (q >= 8.f) return s | (1u << 3);  // rounds up to 2^-6
        return s | (unsigned)(int)q;
    }
}

// ---- fp8 e4m3fn pair decode ----
__device__ __forceinline__ v2f dec2lo(unsigned v) {
#if __has_builtin(__builtin_amdgcn_cvt_pk_f32_fp8)
    return __builtin_amdgcn_cvt_pk_f32_fp8((int)v, false);
#else
    unsigned b0 = v & 0xffu, b1 = (v >> 8) & 0xffu;
    v2f r;
    r.x = __uint_as_float(((b0 & 0x80u) << 24) | ((b0 & 0x7fu) << 20)) * 1.3292279957849159e36f;
    r.y = __uint_as_float(((b1 & 0x80u) << 24) | ((b1 & 0x7fu) << 20)) * 1.3292279957849159e36f;
    return r;
#endif
}
__device__ __forceinline__ v2f dec2hi(unsigned v) {
#if __has_builtin(__builtin_amdgcn_cvt_pk_f32_fp8)
    return __builtin_amdgcn_cvt_pk_f32_fp8((int)v, true);
#else
    unsigned b0 = (v >> 16) & 0xffu, b1 = (v >> 24) & 0xffu;
    v2f r;
    r.x = __uint_as_float(((b0 & 0x80u) << 24) | ((b0 & 0x7fu) << 20)) * 1.3292279957849159e36f;
    r.y = __uint_as_float(((b1 & 0x80u) << 24) | ((b1 & 0x7fu) << 20)) * 1.3292279957849159e36f;
    return r;
#endif
}

// ---------------- K0: repack w_hh (f32 -> fp8 e4m3, scaled x64) ----------------
// out[((dir*64 + kq)*1024 + r)] : byte b = fp8(64 * w[r][4*kq+b])
__global__ __launch_bounds__(256) void cvt_whh_fp8(
    const float* __restrict__ wf, const float* __restrict__ wb,
    unsigned int* __restrict__ out)
{
    int d = blockIdx.x * 256 + threadIdx.x;   // 0 .. 131071
    int r   = d & 1023;
    int kq  = (d >> 10) & 63;
    int dir = d >> 16;
    const float* w = dir ? wb : wf;
    const float* src = w + (size_t)r * 256 + kq * 4;
    unsigned o = 0;
    #pragma unroll
    for (int i = 0; i < 4; ++i) o |= enc8(src[i] * 64.f) << (8 * i);
    out[d] = o;
}

// ---------------- K1: fused gather + input projection GEMM ----------------
// xp[dir][m][n] = emb[sent[m]] . w_ih_dir[n] + b_ih[n] + b_hh[n]
// M=8192, N=2048 (2 dirs x 1024), K=300.  BM=BN=128, BK=60.
__global__ __launch_bounds__(256) void xp_gemm(
    const int* __restrict__ sent, const float* __restrict__ emb,
    const float* __restrict__ w_ih_f, const float* __restrict__ b_ih_f, const float* __restrict__ b_hh_f,
    const float* __restrict__ w_ih_b, const float* __restrict__ b_ih_b, const float* __restrict__ b_hh_b,
    float* __restrict__ xp)
{
    __shared__ float as[60][128];
    __shared__ float bs[60][128];
    __shared__ int sidx[128];
    const int tid = threadIdx.x;
    const int m0 = blockIdx.x * 128;
    const int nt = blockIdx.y;
    const int dir = nt >> 3;
    const int n0 = (nt & 7) * 128;
    const float* w_ih = dir ? w_ih_b : w_ih_f;
    const float* bi = dir ? b_ih_b : b_ih_f;
    const float* bh = dir ? b_hh_b : b_hh_f;
    if (tid < 128) sidx[tid] = sent[m0 + tid];
    __syncthreads();
    const int lr = tid >> 1;
    const int lh = tid & 1;
    const int rb = (tid & 15) * 4;
    const int cb = (tid >> 4) * 4;
    float acc[8][8] = {};
    const float* asrc = emb  + (size_t)sidx[lr] * 300 + lh * 30;
    const float* bsrc = w_ih + (size_t)(n0 + lr) * 300 + lh * 30;
    for (int kc = 0; kc < 5; ++kc) {
        #pragma unroll
        for (int i = 0; i < 15; ++i) {
            float2 va = *(const float2*)(asrc + 2 * i);
            as[lh * 30 + 2 * i][lr]     = va.x;
            as[lh * 30 + 2 * i + 1][lr] = va.y;
            float2 vb = *(const float2*)(bsrc + 2 * i);
            bs[lh * 30 + 2 * i][lr]     = vb.x;
            bs[lh * 30 + 2 * i + 1][lr] = vb.y;
        }
        asrc += 60; bsrc += 60;
        __syncthreads();
        #pragma unroll 4
        for (int kk = 0; kk < 60; ++kk) {
            float a[8], b[8];
            *(float4*)(a)     = *(const float4*)&as[kk][rb];
            *(float4*)(a + 4) = *(const float4*)&as[kk][64 + rb];
            *(float4*)(b)     = *(const float4*)&bs[kk][cb];
            *(float4*)(b + 4) = *(const float4*)&bs[kk][64 + cb];
            #pragma unroll
            for (int i = 0; i < 8; ++i)
                #pragma unroll
                for (int jj = 0; jj < 8; ++jj)
                    acc[i][jj] += a[i] * b[jj];
        }
        __syncthreads();
    }
    float bias[8];
    #pragma unroll
    for (int jj = 0; jj < 4; ++jj) {
        bias[jj]     = bi[n0 + cb + jj]      + bh[n0 + cb + jj];
        bias[4 + jj] = bi[n0 + 64 + cb + jj] + bh[n0 + 64 + cb + jj];
    }
    float* outp = xp + (size_t)dir * 8388608 + (size_t)m0 * 1024 + n0;
    #pragma unroll
    for (int i = 0; i < 8; ++i) {
        int r = (i < 4) ? (rb + i) : (64 + rb + i - 4);
        float4 o0 = make_float4(acc[i][0] + bias[0], acc[i][1] + bias[1],
                                acc[i][2] + bias[2], acc[i][3] + bias[3]);
        float4 o1 = make_float4(acc[i][4] + bias[4], acc[i][5] + bias[5],
                                acc[i][6] + bias[6], acc[i][7] + bias[7]);
        *(float4*)&outp[(size_t)r * 1024 + cb]      = o0;
        *(float4*)&outp[(size_t)r * 1024 + 64 + cb] = o1;
    }
}

// ---------------- K2: LSTM recurrence, fp8 weights register-resident ----------------
// 128 blocks = (dir, batch). 512 threads; thread t owns gate rows t and t+512.
// Weights: 2 x 64 packed-fp8 dwords per thread, held in VGPRs for all 128 steps.
// NOTE: no min-waves arg in launch_bounds — a 128-VGPR cap forces the weight
// arrays to scratch (round-2 lesson: 4.7 GB HBM traffic, 5.3x slower).
__global__ __launch_bounds__(512) void lstm_rec(
    const float* __restrict__ xp, const unsigned int* __restrict__ w8,
    float* __restrict__ lstm_out)
{
    const int bid = blockIdx.x;
    const int dir = bid >> 6;
    const int b = bid & 63;
    const int t = threadIdx.x;
    __shared__ __align__(16) float hs[256];
    __shared__ float gs[1024];

    unsigned wA[64], wB[64];
    const unsigned* wp = w8 + (size_t)dir * 65536;
    #pragma unroll
    for (int kq = 0; kq < 64; ++kq) {
        wA[kq] = wp[kq * 1024 + t];
        wB[kq] = wp[kq * 1024 + t + 512];
    }
    float c = 0.f;
    if (t < 256) hs[t] = 0.f;
    const float* xpb = xp + (size_t)dir * 8388608 + (size_t)b * 131072;
    const int dl = dir ? -1 : 1;
    int l = dir ? 127 : 0;
    float xr0 = xpb[l * 1024 + t];
    float xr1 = xpb[l * 1024 + t + 512];
    __syncthreads();

    for (int s = 0; s < 128; ++s) {
        float nx0 = 0.f, nx1 = 0.f;
        if (s < 127) {                        // prefetch next step's xp
            const float* xn = xpb + (size_t)(l + dl) * 1024;
            nx0 = xn[t]; nx1 = xn[t + 512];
        }
        v2f accA = {0.f, 0.f}, accB = {0.f, 0.f};
        #pragma unroll
        for (int kq = 0; kq < 64; ++kq) {
            float4 h4 = *((const float4*)hs + kq);   // uniform-address broadcast
            v2f h01; h01.x = h4.x; h01.y = h4.y;
            v2f h23; h23.x = h4.z; h23.y = h4.w;
            unsigned wa = wA[kq], wb_ = wB[kq];
            accA += dec2lo(wa) * h01;                // v_pk_fma_f32
            accA += dec2hi(wa) * h23;
            accB += dec2lo(wb_) * h01;
            accB += dec2hi(wb_) * h23;
        }
        gs[t]       = (accA.x + accA.y) * 0.015625f + xr0;   // /64 undoes encode scale
        gs[t + 512] = (accB.x + accB.y) * 0.015625f + xr1;
        __syncthreads();
        if (t < 256) {
            float gi = gs[t], gf = gs[t + 256], gg = gs[t + 512], go = gs[t + 768];
            c = sigmf(gf) * c + sigmf(gi) * tanhfast(gg);
            float h = sigmf(go) * tanhfast(c);
            hs[t] = h;
            lstm_out[(size_t)(b * 128 + l) * 512 + dir * 256 + t] = h;
        }
        __syncthreads();
        xr0 = nx0; xr1 = nx1; l += dl;
    }
}

// ---------------- K3: emissions GEMM ----------------
__global__ __launch_bounds__(256) void emis_gemm(
    const float* __restrict__ lo, const float* __restrict__ w_out,
    const float* __restrict__ b_out, float* __restrict__ em)
{
    __shared__ float as[64][64];
    __shared__ float bs[64][64];
    const int tid = threadIdx.x;
    const int m0 = blockIdx.x * 64;
    const int mr = tid & 63;
    const int kq = tid >> 6;
    const int rb = (tid & 15) * 4;
    const int cb = (tid >> 4) * 4;
    float acc[4][4] = {};
    for (int kc = 0; kc < 8; ++kc) {
        const int k0 = kc * 64;
        #pragma unroll
        for (int i = 0; i < 4; ++i) {
            const int k = kq * 16 + 4 * i;
            float4 va = *(const float4*)&lo[(size_t)(m0 + mr) * 512 + k0 + k];
            as[k][mr] = va.x; as[k + 1][mr] = va.y; as[k + 2][mr] = va.z; as[k + 3][mr] = va.w;
            float4 vb = *(const float4*)&w_out[(size_t)mr * 512 + k0 + k];
            bs[k][mr] = vb.x; bs[k + 1][mr] = vb.y; bs[k + 2][mr] = vb.z; bs[k + 3][mr] = vb.w;
        }
        __syncthreads();
        #pragma unroll 8
        for (int kk = 0; kk < 64; ++kk) {
            float a[4], bb[4];
            *(float4*)a  = *(const float4*)&as[kk][rb];
            *(float4*)bb = *(const float4*)&bs[kk][cb];
            #pragma unroll
            for (int i = 0; i < 4; ++i)
                #pragma unroll
                for (int jj = 0; jj < 4; ++jj)
                    acc[i][jj] += a[i] * bb[jj];
        }
        __syncthreads();
    }
    float4 bo = *(const float4*)&b_out[cb];
    #pragma unroll
    for (int i = 0; i < 4; ++i) {
        float4 o = make_float4(acc[i][0] + bo.x, acc[i][1] + bo.y,
                               acc[i][2] + bo.z, acc[i][3] + bo.w);
        *(float4*)&em[(size_t)(m0 + rb + i) * 64 + cb] = o;
    }
}

// ---------------- K4: CRF numerator + forward algorithm ----------------
__global__ __launch_bounds__(256) void crf_kernel(
    const float* __restrict__ em, const int* __restrict__ tags,
    const float* __restrict__ start_t, const float* __restrict__ end_t,
    const float* __restrict__ trans, float* __restrict__ nll)
{
    const int b = blockIdx.x;
    const int tid = threadIdx.x;
    const int j = tid & 63;
    const int q = tid >> 6;
    __shared__ float s_lds[64];
    __shared__ float part[4][64];
    __shared__ float m_sh, num_sh;
    float tr[16];
    #pragma unroll
    for (int ii = 0; ii < 16; ++ii) tr[ii] = trans[(q * 16 + ii) * 64 + j];
    const float* emb_b = em + (size_t)b * 8192;
    const int* tg_b = tags + b * 128;
    float numpart = 0.f;
    if (tid < 128) {
        int l = tid;
        int tg = tg_b[l];
        numpart = emb_b[l * 64 + tg];
        if (l < 127) numpart += trans[tg * 64 + tg_b[l + 1]];
        if (l == 0)  numpart += start_t[tg];
        if (l == 127) numpart += end_t[tg];
    }
    float red = numpart;
    #pragma unroll
    for (int off = 32; off >= 1; off >>= 1) red += __shfl_xor(red, off);
    if (j == 0) part[q][0] = red;
    if (q == 0) s_lds[j] = start_t[j] + emb_b[j];
    __syncthreads();
    if (tid == 0) num_sh = part[0][0] + part[1][0] + part[2][0] + part[3][0];
    __syncthreads();
    for (int l = 1; l < 128; ++l) {
        if (q == 0) {
            float v = s_lds[j];
            #pragma unroll
            for (int off = 32; off >= 1; off >>= 1) v = fmaxf(v, __shfl_xor(v, off));
            if (j == 0) m_sh = v;
        }
        __syncthreads();
        const float m = m_sh;
        float sv[16];
        #pragma unroll
        for (int t4 = 0; t4 < 4; ++t4) {
            float4 v = *(const float4*)&s_lds[q * 16 + 4 * t4];
            sv[4 * t4] = v.x; sv[4 * t4 + 1] = v.y; sv[4 * t4 + 2] = v.z; sv[4 * t4 + 3] = v.w;
        }
        float acc = 0.f;
        #pragma unroll
        for (int ii = 0; ii < 16; ++ii) acc += __expf(sv[ii] + tr[ii] - m);
        part[q][j] = acc;
        __syncthreads();
        if (q == 0) {
            float t = part[0][j] + part[1][j] + part[2][j] + part[3][j];
            s_lds[j] = m + __logf(t) + emb_b[l * 64 + j];
        }
    }
    if (q == 0) {
        float v = s_lds[j] + end_t[j];
        float mm = v;
        #pragma unroll
        for (int off = 32; off >= 1; off >>= 1) mm = fmaxf(mm, __shfl_xor(mm, off));
        float e = __expf(v - mm);
        #pragma unroll
        for (int off = 32; off >= 1; off >>= 1) e += __shfl_xor(e, off);
        if (j == 0) nll[b] = (mm + __logf(e)) - num_sh;
    }
}

// ---------------- K5: final mean ----------------
__global__ void finalize(const float* __restrict__ nll, float* __restrict__ out)
{
    int j = threadIdx.x;
    float v = nll[j];
    #pragma unroll
    for (int off = 32; off >= 1; off >>= 1) v += __shfl_xor(v, off);
    if (j == 0) out[0] = v * (1.f / 64.f);
}

extern "C" void kernel_launch(void* const* d_in, const int* in_sizes, int n_in,
                              void* d_out, int out_size, void* d_ws, size_t ws_size,
                              hipStream_t stream) {
    const int* sent      = (const int*)d_in[0];
    const int* tags      = (const int*)d_in[1];
    const float* emb     = (const float*)d_in[2];
    const float* w_ih_f  = (const float*)d_in[3];
    const float* w_hh_f  = (const float*)d_in[4];
    const float* b_ih_f  = (const float*)d_in[5];
    const float* b_hh_f  = (const float*)d_in[6];
    const float* w_ih_b  = (const float*)d_in[7];
    const float* w_hh_b  = (const float*)d_in[8];
    const float* b_ih_b  = (const float*)d_in[9];
    const float* b_hh_b  = (const float*)d_in[10];
    const float* w_out   = (const float*)d_in[11];
    const float* b_out   = (const float*)d_in[12];
    const float* start_t = (const float*)d_in[13];
    const float* end_t   = (const float*)d_in[14];
    const float* trans   = (const float*)d_in[15];

    float* ws = (float*)d_ws;
    float* xp        = ws + XP_OFF;
    float* lstm_out  = ws + LSTM_OFF;
    float* em        = ws + EM_OFF;
    unsigned int* w8 = (unsigned int*)(ws + WBF_OFF);
    float* nll       = ws + NLL_OFF;

    cvt_whh_fp8<<<dim3(512), dim3(256), 0, stream>>>(w_hh_f, w_hh_b, w8);
    xp_gemm<<<dim3(64, 16), dim3(256), 0, stream>>>(sent, emb,
        w_ih_f, b_ih_f, b_hh_f, w_ih_b, b_ih_b, b_hh_b, xp);
    lstm_rec<<<dim3(128), dim3(512), 0, stream>>>(xp, w8, lstm_out);
    emis_gemm<<<dim3(128), dim3(256), 0, stream>>>(lstm_out, w_out, b_out, em);
    crf_kernel<<<dim3(64), dim3(256), 0, stream>>>(em, tags, start_t, end_t, trans, nll);
    finalize<<<dim3(1), dim3(64), 0, stream>>>(nll, (float*)d_out);
}

// Round 4
// 2994.873 us; speedup vs baseline: 1.9692x; 1.5483x over previous
//
#include <hip/hip_runtime.h>

// Problem: BiLSTM-CRF tagger NLL (forward only).
// B=64, L=128, E=300, H=256 (per dir), 4H=1024, T=64, V=50000.
// Output: single f32 scalar = mean(log_z - numerator).
//
// ws layout (float units):
//   XP_OFF   = 0           : xp[2][8192][1024]   (input projections, biases folded)
//   LSTM_OFF = 16777216    : lstm_out[8192][512] (cols 0-255 fwd h, 256-511 bwd h)
//   EM_OFF   = 20971520    : emissions[8192][64]
//   WBF_OFF  = 21495808    : w_hh fp8 repacked, 2*64*1024 dwords (512 KB)
//   NLL_OFF  = 21757952    : per-batch nll [64]

#define XP_OFF   0
#define LSTM_OFF 16777216
#define EM_OFF   20971520
#define WBF_OFF  21495808
#define NLL_OFF  21757952

typedef float v2f __attribute__((ext_vector_type(2)));

__device__ __forceinline__ float sigmf(float x) { return 1.f / (1.f + __expf(-x)); }
__device__ __forceinline__ float tanhfast(float x) {
    float t = __expf(2.f * x);
    return 1.f - 2.f / (t + 1.f);
}

// ---- fp8 e4m3fn encode (RNE), |x| <= 4.0 guaranteed by caller ----
__device__ __forceinline__ unsigned enc8(float x) {
    unsigned s = (__float_as_uint(x) >> 31) << 7;
    float a = fabsf(x);
    if (a >= 0.015625f) {                    // normal: 2^-6 .. 4.0
        int e; float m = frexpf(a, &e);      // a = m*2^e, m in [0.5,1)
        float q = rintf(m * 16.f);           // in [8,16]
        if (q >= 16.f) { q = 8.f; e += 1; }
        int E = e - 1 + 7;
        return s | (unsigned)(E << 3) | (unsigned)((int)q - 8);
    } else {                                 // denormal: multiples of 2^-9
        float q = rintf(a * 512.f);          // 0..8
        if (q >= 8.f) return s | (1u << 3);  // rounds up to 2^-6
        return s | (unsigned)(int)q;
    }
}

// ---- fp8 e4m3fn pair decode ----
__device__ __forceinline__ v2f dec2lo(unsigned v) {
#if __has_builtin(__builtin_amdgcn_cvt_pk_f32_fp8)
    return __builtin_amdgcn_cvt_pk_f32_fp8((int)v, false);
#else
    unsigned b0 = v & 0xffu, b1 = (v >> 8) & 0xffu;
    v2f r;
    r.x = __uint_as_float(((b0 & 0x80u) << 24) | ((b0 & 0x7fu) << 20)) * 1.3292279957849159e36f;
    r.y = __uint_as_float(((b1 & 0x80u) << 24) | ((b1 & 0x7fu) << 20)) * 1.3292279957849159e36f;
    return r;
#endif
}
__device__ __forceinline__ v2f dec2hi(unsigned v) {
#if __has_builtin(__builtin_amdgcn_cvt_pk_f32_fp8)
    return __builtin_amdgcn_cvt_pk_f32_fp8((int)v, true);
#else
    unsigned b0 = (v >> 16) & 0xffu, b1 = (v >> 24) & 0xffu;
    v2f r;
    r.x = __uint_as_float(((b0 & 0x80u) << 24) | ((b0 & 0x7fu) << 20)) * 1.3292279957849159e36f;
    r.y = __uint_as_float(((b1 & 0x80u) << 24) | ((b1 & 0x7fu) << 20)) * 1.3292279957849159e36f;
    return r;
#endif
}

// ---------------- K0: repack w_hh (f32 -> fp8 e4m3, scaled x64) ----------------
// Layout matches lstm_rec's per-thread ownership:
//   out[(dir*64 + d)*1024 + t], thread t: kh=t>>9, tt=t&511;
//   d<32 -> row tt, d>=32 -> row tt+512; k = kh*128 + (d&31)*4 .. +3
__global__ __launch_bounds__(256) void cvt_whh_fp8(
    const float* __restrict__ wf, const float* __restrict__ wb,
    unsigned int* __restrict__ out)
{
    int idx = blockIdx.x * 256 + threadIdx.x;   // 0 .. 131071
    int t   = idx & 1023;
    int d   = (idx >> 10) & 63;
    int dir = idx >> 16;
    const float* w = dir ? wb : wf;
    int kh = t >> 9, tt = t & 511;
    int row = (d < 32) ? tt : (tt + 512);
    int kbase = kh * 128 + (d & 31) * 4;
    const float* src = w + (size_t)row * 256 + kbase;
    unsigned o = 0;
    #pragma unroll
    for (int i = 0; i < 4; ++i) o |= enc8(src[i] * 64.f) << (8 * i);
    out[idx] = o;
}

// ---------------- K1: fused gather + input projection GEMM ----------------
// xp[dir][m][n] = emb[sent[m]] . w_ih_dir[n] + b_ih[n] + b_hh[n]
// M=8192, N=2048 (2 dirs x 1024), K=300.  BM=BN=128, BK=60.
__global__ __launch_bounds__(256) void xp_gemm(
    const int* __restrict__ sent, const float* __restrict__ emb,
    const float* __restrict__ w_ih_f, const float* __restrict__ b_ih_f, const float* __restrict__ b_hh_f,
    const float* __restrict__ w_ih_b, const float* __restrict__ b_ih_b, const float* __restrict__ b_hh_b,
    float* __restrict__ xp)
{
    __shared__ float as[60][128];
    __shared__ float bs[60][128];
    __shared__ int sidx[128];
    const int tid = threadIdx.x;
    const int m0 = blockIdx.x * 128;
    const int nt = blockIdx.y;
    const int dir = nt >> 3;
    const int n0 = (nt & 7) * 128;
    const float* w_ih = dir ? w_ih_b : w_ih_f;
    const float* bi = dir ? b_ih_b : b_ih_f;
    const float* bh = dir ? b_hh_b : b_hh_f;
    if (tid < 128) sidx[tid] = sent[m0 + tid];
    __syncthreads();
    const int lr = tid >> 1;
    const int lh = tid & 1;
    const int rb = (tid & 15) * 4;
    const int cb = (tid >> 4) * 4;
    float acc[8][8] = {};
    const float* asrc = emb  + (size_t)sidx[lr] * 300 + lh * 30;
    const float* bsrc = w_ih + (size_t)(n0 + lr) * 300 + lh * 30;
    for (int kc = 0; kc < 5; ++kc) {
        #pragma unroll
        for (int i = 0; i < 15; ++i) {
            float2 va = *(const float2*)(asrc + 2 * i);
            as[lh * 30 + 2 * i][lr]     = va.x;
            as[lh * 30 + 2 * i + 1][lr] = va.y;
            float2 vb = *(const float2*)(bsrc + 2 * i);
            bs[lh * 30 + 2 * i][lr]     = vb.x;
            bs[lh * 30 + 2 * i + 1][lr] = vb.y;
        }
        asrc += 60; bsrc += 60;
        __syncthreads();
        #pragma unroll 4
        for (int kk = 0; kk < 60; ++kk) {
            float a[8], b[8];
            *(float4*)(a)     = *(const float4*)&as[kk][rb];
            *(float4*)(a + 4) = *(const float4*)&as[kk][64 + rb];
            *(float4*)(b)     = *(const float4*)&bs[kk][cb];
            *(float4*)(b + 4) = *(const float4*)&bs[kk][64 + cb];
            #pragma unroll
            for (int i = 0; i < 8; ++i)
                #pragma unroll
                for (int jj = 0; jj < 8; ++jj)
                    acc[i][jj] += a[i] * b[jj];
        }
        __syncthreads();
    }
    float bias[8];
    #pragma unroll
    for (int jj = 0; jj < 4; ++jj) {
        bias[jj]     = bi[n0 + cb + jj]      + bh[n0 + cb + jj];
        bias[4 + jj] = bi[n0 + 64 + cb + jj] + bh[n0 + 64 + cb + jj];
    }
    float* outp = xp + (size_t)dir * 8388608 + (size_t)m0 * 1024 + n0;
    #pragma unroll
    for (int i = 0; i < 8; ++i) {
        int r = (i < 4) ? (rb + i) : (64 + rb + i - 4);
        float4 o0 = make_float4(acc[i][0] + bias[0], acc[i][1] + bias[1],
                                acc[i][2] + bias[2], acc[i][3] + bias[3]);
        float4 o1 = make_float4(acc[i][4] + bias[4], acc[i][5] + bias[5],
                                acc[i][6] + bias[6], acc[i][7] + bias[7]);
        *(float4*)&outp[(size_t)r * 1024 + cb]      = o0;
        *(float4*)&outp[(size_t)r * 1024 + 64 + cb] = o1;
    }
}

// ---------------- K2: LSTM recurrence, fp8 weights register-resident ----------------
// 128 blocks = (dir, batch). 1024 threads.
// Thread t: kh = t>>9 (k half), tt = t&511; owns gate rows {tt, tt+512} over
// k in [kh*128, kh*128+128)  ->  64 packed-fp8 dwords in VGPRs (fits the
// 128-VGPR budget the compiler enforces at 4 waves/EU; rounds 2-3 showed a
// 128-dword array spills to scratch = 4.6 GB HBM traffic).
// Row partials for the two k-halves are summed via LDS part[2][1024].
__global__ __launch_bounds__(1024) void lstm_rec(
    const float* __restrict__ xp, const unsigned int* __restrict__ w8,
    float* __restrict__ lstm_out)
{
    const int bid = blockIdx.x;
    const int dir = bid >> 6;
    const int b = bid & 63;
    const int t = threadIdx.x;
    const int kh = t >> 9;
    const int tt = t & 511;
    __shared__ __align__(16) float hs[256];
    __shared__ float part[2][1024];

    unsigned wreg[64];
    const unsigned* wp = w8 + (size_t)dir * 65536;
    #pragma unroll
    for (int d = 0; d < 64; ++d) wreg[d] = wp[d * 1024 + t];

    float c = 0.f;
    if (t < 256) hs[t] = 0.f;
    const float* xpb = xp + (size_t)dir * 8388608 + (size_t)b * 131072;
    const int dl = dir ? -1 : 1;
    int l = dir ? 127 : 0;
    float xr0 = 0.f, xr1 = 0.f;
    if (t < 512) {                            // only k-half-0 threads carry xp
        xr0 = xpb[l * 1024 + tt];
        xr1 = xpb[l * 1024 + tt + 512];
    }
    __syncthreads();

    for (int s = 0; s < 128; ++s) {
        float nx0 = 0.f, nx1 = 0.f;
        if (s < 127 && t < 512) {             // prefetch next step's xp
            const float* xn = xpb + (size_t)(l + dl) * 1024;
            nx0 = xn[tt]; nx1 = xn[tt + 512];
        }
        v2f a0 = {0.f, 0.f}, a1 = {0.f, 0.f};
        const float4* h4p = (const float4*)hs + kh * 32;
        #pragma unroll
        for (int i = 0; i < 32; ++i) {
            float4 h4 = h4p[i];               // uniform-address broadcast
            v2f h01; h01.x = h4.x; h01.y = h4.y;
            v2f h23; h23.x = h4.z; h23.y = h4.w;
            unsigned w0 = wreg[i], w1 = wreg[i + 32];
            a0 += dec2lo(w0) * h01;           // v_pk_fma_f32
            a0 += dec2hi(w0) * h23;
            a1 += dec2lo(w1) * h01;
            a1 += dec2hi(w1) * h23;
        }
        float p0 = (a0.x + a0.y) * 0.015625f; // /64 undoes encode scale
        float p1 = (a1.x + a1.y) * 0.015625f;
        if (t < 512) {                        // fold xp into k-half-0 partial
            part[0][tt]       = p0 + xr0;
            part[0][tt + 512] = p1 + xr1;
        } else {
            part[1][tt]       = p0;
            part[1][tt + 512] = p1;
        }
        __syncthreads();
        if (t < 256) {
            float gi = part[0][t]       + part[1][t];
            float gf = part[0][t + 256] + part[1][t + 256];
            float gg = part[0][t + 512] + part[1][t + 512];
            float go = part[0][t + 768] + part[1][t + 768];
            c = sigmf(gf) * c + sigmf(gi) * tanhfast(gg);
            float h = sigmf(go) * tanhfast(c);
            hs[t] = h;
            lstm_out[(size_t)(b * 128 + l) * 512 + dir * 256 + t] = h;
        }
        __syncthreads();
        xr0 = nx0; xr1 = nx1; l += dl;
    }
}

// ---------------- K3: emissions GEMM ----------------
__global__ __launch_bounds__(256) void emis_gemm(
    const float* __restrict__ lo, const float* __restrict__ w_out,
    const float* __restrict__ b_out, float* __restrict__ em)
{
    __shared__ float as[64][64];
    __shared__ float bs[64][64];
    const int tid = threadIdx.x;
    const int m0 = blockIdx.x * 64;
    const int mr = tid & 63;
    const int kq = tid >> 6;
    const int rb = (tid & 15) * 4;
    const int cb = (tid >> 4) * 4;
    float acc[4][4] = {};
    for (int kc = 0; kc < 8; ++kc) {
        const int k0 = kc * 64;
        #pragma unroll
        for (int i = 0; i < 4; ++i) {
            const int k = kq * 16 + 4 * i;
            float4 va = *(const float4*)&lo[(size_t)(m0 + mr) * 512 + k0 + k];
            as[k][mr] = va.x; as[k + 1][mr] = va.y; as[k + 2][mr] = va.z; as[k + 3][mr] = va.w;
            float4 vb = *(const float4*)&w_out[(size_t)mr * 512 + k0 + k];
            bs[k][mr] = vb.x; bs[k + 1][mr] = vb.y; bs[k + 2][mr] = vb.z; bs[k + 3][mr] = vb.w;
        }
        __syncthreads();
        #pragma unroll 8
        for (int kk = 0; kk < 64; ++kk) {
            float a[4], bb[4];
            *(float4*)a  = *(const float4*)&as[kk][rb];
            *(float4*)bb = *(const float4*)&bs[kk][cb];
            #pragma unroll
            for (int i = 0; i < 4; ++i)
                #pragma unroll
                for (int jj = 0; jj < 4; ++jj)
                    acc[i][jj] += a[i] * bb[jj];
        }
        __syncthreads();
    }
    float4 bo = *(const float4*)&b_out[cb];
    #pragma unroll
    for (int i = 0; i < 4; ++i) {
        float4 o = make_float4(acc[i][0] + bo.x, acc[i][1] + bo.y,
                               acc[i][2] + bo.z, acc[i][3] + bo.w);
        *(float4*)&em[(size_t)(m0 + rb + i) * 64 + cb] = o;
    }
}

// ---------------- K4: CRF numerator + forward algorithm ----------------
__global__ __launch_bounds__(256) void crf_kernel(
    const float* __restrict__ em, const int* __restrict__ tags,
    const float* __restrict__ start_t, const float* __restrict__ end_t,
    const float* __restrict__ trans, float* __restrict__ nll)
{
    const int b = blockIdx.x;
    const int tid = threadIdx.x;
    const int j = tid & 63;
    const int q = tid >> 6;
    __shared__ float s_lds[64];
    __shared__ float part[4][64];
    __shared__ float m_sh, num_sh;
    float tr[16];
    #pragma unroll
    for (int ii = 0; ii < 16; ++ii) tr[ii] = trans[(q * 16 + ii) * 64 + j];
    const float* emb_b = em + (size_t)b * 8192;
    const int* tg_b = tags + b * 128;
    float numpart = 0.f;
    if (tid < 128) {
        int l = tid;
        int tg = tg_b[l];
        numpart = emb_b[l * 64 + tg];
        if (l < 127) numpart += trans[tg * 64 + tg_b[l + 1]];
        if (l == 0)  numpart += start_t[tg];
        if (l == 127) numpart += end_t[tg];
    }
    float red = numpart;
    #pragma unroll
    for (int off = 32; off >= 1; off >>= 1) red += __shfl_xor(red, off);
    if (j == 0) part[q][0] = red;
    if (q == 0) s_lds[j] = start_t[j] + emb_b[j];
    __syncthreads();
    if (tid == 0) num_sh = part[0][0] + part[1][0] + part[2][0] + part[3][0];
    __syncthreads();
    for (int l = 1; l < 128; ++l) {
        if (q == 0) {
            float v = s_lds[j];
            #pragma unroll
            for (int off = 32; off >= 1; off >>= 1) v = fmaxf(v, __shfl_xor(v, off));
            if (j == 0) m_sh = v;
        }
        __syncthreads();
        const float m = m_sh;
        float sv[16];
        #pragma unroll
        for (int t4 = 0; t4 < 4; ++t4) {
            float4 v = *(const float4*)&s_lds[q * 16 + 4 * t4];
            sv[4 * t4] = v.x; sv[4 * t4 + 1] = v.y; sv[4 * t4 + 2] = v.z; sv[4 * t4 + 3] = v.w;
        }
        float acc = 0.f;
        #pragma unroll
        for (int ii = 0; ii < 16; ++ii) acc += __expf(sv[ii] + tr[ii] - m);
        part[q][j] = acc;
        __syncthreads();
        if (q == 0) {
            float t = part[0][j] + part[1][j] + part[2][j] + part[3][j];
            s_lds[j] = m + __logf(t) + emb_b[l * 64 + j];
        }
    }
    if (q == 0) {
        float v = s_lds[j] + end_t[j];
        float mm = v;
        #pragma unroll
        for (int off = 32; off >= 1; off >>= 1) mm = fmaxf(mm, __shfl_xor(mm, off));
        float e = __expf(v - mm);
        #pragma unroll
        for (int off = 32; off >= 1; off >>= 1) e += __shfl_xor(e, off);
        if (j == 0) nll[b] = (mm + __logf(e)) - num_sh;
    }
}

// ---------------- K5: final mean ----------------
__global__ void finalize(const float* __restrict__ nll, float* __restrict__ out)
{
    int j = threadIdx.x;
    float v = nll[j];
    #pragma unroll
    for (int off = 32; off >= 1; off >>= 1) v += __shfl_xor(v, off);
    if (j == 0) out[0] = v * (1.f / 64.f);
}

extern "C" void kernel_launch(void* const* d_in, const int* in_sizes, int n_in,
                              void* d_out, int out_size, void* d_ws, size_t ws_size,
                              hipStream_t stream) {
    const int* sent      = (const int*)d_in[0];
    const int* tags      = (const int*)d_in[1];
    const float* emb     = (const float*)d_in[2];
    const float* w_ih_f  = (const float*)d_in[3];
    const float* w_hh_f  = (const float*)d_in[4];
    const float* b_ih_f  = (const float*)d_in[5];
    const float* b_hh_f  = (const float*)d_in[6];
    const float* w_ih_b  = (const float*)d_in[7];
    const float* w_hh_b  = (const float*)d_in[8];
    const float* b_ih_b  = (const float*)d_in[9];
    const float* b_hh_b  = (const float*)d_in[10];
    const float* w_out   = (const float*)d_in[11];
    const float* b_out   = (const float*)d_in[12];
    const float* start_t = (const float*)d_in[13];
    const float* end_t   = (const float*)d_in[14];
    const float* trans   = (const float*)d_in[15];

    float* ws = (float*)d_ws;
    float* xp        = ws + XP_OFF;
    float* lstm_out  = ws + LSTM_OFF;
    float* em        = ws + EM_OFF;
    unsigned int* w8 = (unsigned int*)(ws + WBF_OFF);
    float* nll       = ws + NLL_OFF;

    cvt_whh_fp8<<<dim3(512), dim3(256), 0, stream>>>(w_hh_f, w_hh_b, w8);
    xp_gemm<<<dim3(64, 16), dim3(256), 0, stream>>>(sent, emb,
        w_ih_f, b_ih_f, b_hh_f, w_ih_b, b_ih_b, b_hh_b, xp);
    lstm_rec<<<dim3(128), dim3(1024), 0, stream>>>(xp, w8, lstm_out);
    emis_gemm<<<dim3(128), dim3(256), 0, stream>>>(lstm_out, w_out, b_out, em);
    crf_kernel<<<dim3(64), dim3(256), 0, stream>>>(em, tags, start_t, end_t, trans, nll);
    finalize<<<dim3(1), dim3(64), 0, stream>>>(nll, (float*)d_out);
}